// Round 2
// baseline (577.320 us; speedup 1.0000x reference)
//
#include <hip/hip_runtime.h>
#include <hip/hip_bf16.h>

typedef unsigned short u16;
typedef unsigned int   u32;

#define N_NODES 10000
#define N_EDGES 160000
#define HDIM    512
#define KDIM    1024
#define NPAD    10112   // 79 * 128

typedef __attribute__((ext_vector_type(8))) __bf16 bf16x8;
typedef __attribute__((ext_vector_type(4))) float  f32x4;

__device__ __forceinline__ float bflo(u32 v){ return __builtin_bit_cast(float, v << 16); }
__device__ __forceinline__ float bfhi(u32 v){ return __builtin_bit_cast(float, v & 0xffff0000u); }
__device__ __forceinline__ u16   f2bf(float f){ __hip_bfloat16 h = __float2bfloat16(f); return __builtin_bit_cast(u16, h); }

// ---------------- CSR build ----------------
__global__ void k_zero32(u32* __restrict__ p, int n){
  int i = blockIdx.x*256 + threadIdx.x;
  if (i < n) p[i] = 0u;
}

__global__ void k_hist(const int* __restrict__ dst, int* __restrict__ cnt){
  int e = blockIdx.x*256 + threadIdx.x;
  if (e < N_EDGES) atomicAdd(&cnt[dst[e]], 1);
}

__global__ __launch_bounds__(1024) void k_scan(const int* __restrict__ cnt, int* __restrict__ row_ptr,
                                               int* __restrict__ cursor, float* __restrict__ inv_deg){
  __shared__ int part[1024];
  int t = threadIdx.x;
  int base = t*10;
  int local[10]; int s = 0;
  for (int i=0;i<10;i++){
    int idx = base+i;
    int v = (idx < N_NODES) ? cnt[idx] : 0;
    local[i] = s; s += v;
  }
  part[t] = s;
  __syncthreads();
  for (int off=1; off<1024; off<<=1){
    int v = (t>=off) ? part[t-off] : 0;
    __syncthreads();
    part[t] += v;
    __syncthreads();
  }
  int prev = (t==0) ? 0 : part[t-1];
  for (int i=0;i<10;i++){
    int idx = base+i;
    if (idx < N_NODES){
      int rp = prev + local[i];
      row_ptr[idx] = rp; cursor[idx] = rp;
      int c = cnt[idx];
      inv_deg[idx] = 1.0f / (float)(c > 0 ? c : 1);
    }
  }
  if (t==1023) row_ptr[N_NODES] = part[1023];
}

__global__ void k_fill(const int* __restrict__ src, const int* __restrict__ dst,
                       int* __restrict__ cursor, int* __restrict__ csr_src){
  int e = blockIdx.x*256 + threadIdx.x;
  if (e < N_EDGES){
    int pos = atomicAdd(&cursor[dst[e]], 1);
    csr_src[pos] = src[e];
  }
}

// ---------------- weight concat (fp32 -> bf16): W'[o][0:512]=Wrel[o], W'[o][512:1024]=Wroot[o] ----------------
__global__ __launch_bounds__(256) void k_wcat(const float* __restrict__ wpr, const float* __restrict__ wpo,
                                              const float* __restrict__ wrel, const float* __restrict__ wroot,
                                              const float* __restrict__ wfr, const float* __restrict__ wfo,
                                              u16* __restrict__ Wcat, u16* __restrict__ Wfin){
  int i = blockIdx.x*256 + threadIdx.x;
  if (i < 4*512*512){
    int lyr = i >> 18;
    int r   = i & 262143;
    int o = r >> 9, k = r & 511;
    const float* R = (lyr==0) ? wpr : wrel  + (size_t)(lyr-1)*262144;
    const float* O = (lyr==0) ? wpo : wroot + (size_t)(lyr-1)*262144;
    Wcat[(size_t)lyr*524288 + (size_t)o*KDIM + k]        = f2bf(R[r]);
    Wcat[(size_t)lyr*524288 + (size_t)o*KDIM + HDIM + k] = f2bf(O[r]);
  }
  if (i < 10*512){
    int o = i >> 9, k = i & 511;
    Wfin[o*KDIM + k]        = f2bf(wfr[i]);
    Wfin[o*KDIM + HDIM + k] = f2bf(wfo[i]);
  }
}

// copy x (N x 512 fp32) into A right half (bf16, stride 1024)
__global__ __launch_bounds__(256) void k_copy_x(const float* __restrict__ x, u16* __restrict__ A){
  int c = blockIdx.x*256 + threadIdx.x;
  if (c >= N_NODES*128) return;
  int n = c >> 7, o = (c & 127)*4;
  float4 v = *(const float4*)(x + (size_t)n*HDIM + o);
  ushort4 b;
  b.x = f2bf(v.x); b.y = f2bf(v.y); b.z = f2bf(v.z); b.w = f2bf(v.w);
  *(ushort4*)(A + (size_t)n*KDIM + HDIM + o) = b;
}

// mean-aggregate: A[n][0:512] = inv_deg[n] * sum_{s in nbrs(n)} A[s][512:1024]
__global__ __launch_bounds__(256) void k_agg(const u16* __restrict__ Abuf,
                                             const int* __restrict__ row_ptr, const int* __restrict__ cnt,
                                             const int* __restrict__ csr_src, const float* __restrict__ inv_deg,
                                             u16* __restrict__ Aout){
  int n = blockIdx.x;
  int t = threadIdx.x;               // col pair 2t, 2t+1
  int start = row_ptr[n], num = cnt[n];
  float a0 = 0.f, a1 = 0.f;
  for (int j = 0; j < num; j++){
    int s = csr_src[start + j];
    u32 v = *(const u32*)(Abuf + (size_t)s*KDIM + HDIM + 2*t);
    a0 += bflo(v); a1 += bfhi(v);
  }
  float id = inv_deg[n];
  a0 *= id; a1 *= id;
  u32 o = ((u32)f2bf(a1) << 16) | (u32)f2bf(a0);
  *(u32*)(Aout + (size_t)n*KDIM + 2*t) = o;
}

// ---------------- fused conv GEMM: Hout[row][512+col] = relu( sum_k A[row][k]*W[col][k] ) ----------------
__global__ __launch_bounds__(256) void k_gemm(const u16* __restrict__ A, const u16* __restrict__ W,
                                              u16* __restrict__ Hout){
  __shared__ __align__(16) u16 As[128*32];
  __shared__ __align__(16) u16 Bs[128*32];
  const int t  = threadIdx.x;
  const int l  = t & 63;
  const int wv = t >> 6;
  const int wm = wv >> 1, wn = wv & 1;
  const int m0 = blockIdx.x * 128;
  const int n0 = blockIdx.y * 128;

  const int c0 = t, c1 = t + 256;
  const size_t gA0 = (size_t)(m0 + (c0>>2))*KDIM + ((c0&3)*8);
  const size_t gA1 = (size_t)(m0 + (c1>>2))*KDIM + ((c1&3)*8);
  const size_t gB0 = (size_t)(n0 + (c0>>2))*KDIM + ((c0&3)*8);
  const size_t gB1 = (size_t)(n0 + (c1>>2))*KDIM + ((c1&3)*8);

  f32x4 acc[4][4];
  #pragma unroll
  for (int i=0;i<4;i++)
    #pragma unroll
    for (int j=0;j<4;j++)
      acc[i][j] = f32x4{0.f,0.f,0.f,0.f};

  const int aoff = (wm*64 + (l&15))*32 + (l>>4)*8;
  const int boff = (wn*64 + (l&15))*32 + (l>>4)*8;

  for (int k0 = 0; k0 < KDIM; k0 += 32){
    __builtin_amdgcn_global_load_lds((const __attribute__((address_space(1))) void*)(A + gA0 + k0),
                                     (__attribute__((address_space(3))) void*)(As + c0*8), 16, 0, 0);
    __builtin_amdgcn_global_load_lds((const __attribute__((address_space(1))) void*)(A + gA1 + k0),
                                     (__attribute__((address_space(3))) void*)(As + c1*8), 16, 0, 0);
    __builtin_amdgcn_global_load_lds((const __attribute__((address_space(1))) void*)(W + gB0 + k0),
                                     (__attribute__((address_space(3))) void*)(Bs + c0*8), 16, 0, 0);
    __builtin_amdgcn_global_load_lds((const __attribute__((address_space(1))) void*)(W + gB1 + k0),
                                     (__attribute__((address_space(3))) void*)(Bs + c1*8), 16, 0, 0);
    __syncthreads();
    bf16x8 af[4], bfr[4];
    #pragma unroll
    for (int mt=0; mt<4; mt++)
      af[mt] = *(const bf16x8*)(As + aoff + mt*16*32);
    #pragma unroll
    for (int nt=0; nt<4; nt++)
      bfr[nt] = *(const bf16x8*)(Bs + boff + nt*16*32);
    #pragma unroll
    for (int mt=0; mt<4; mt++)
      #pragma unroll
      for (int nt=0; nt<4; nt++)
        acc[mt][nt] = __builtin_amdgcn_mfma_f32_16x16x32_bf16(af[mt], bfr[nt], acc[mt][nt], 0, 0, 0);
    __syncthreads();
  }

  #pragma unroll
  for (int mt=0; mt<4; mt++){
    #pragma unroll
    for (int nt=0; nt<4; nt++){
      const int col = n0 + wn*64 + nt*16 + (l & 15);
      #pragma unroll
      for (int r=0; r<4; r++){
        const int row = m0 + wm*64 + mt*16 + (l>>4)*4 + r;
        if (row < N_NODES){
          float v = acc[mt][nt][r];
          v = v > 0.f ? v : 0.f;               // relu (also zaps NaN)
          Hout[(size_t)row*KDIM + HDIM + col] = f2bf(v);
        }
      }
    }
  }
}

// ---------------- BN stats over relu'd h (right half of A) ----------------
__global__ __launch_bounds__(256) void k_colstats(const u16* __restrict__ A, float* __restrict__ stats){
  int t = threadIdx.x;
  int r0 = blockIdx.x * 50;
  int r1 = r0 + 50; if (r1 > N_NODES) r1 = N_NODES;
  float s0=0,s1=0,q0=0,q1=0;
  for (int r=r0; r<r1; r++){
    u32 v = *(const u32*)(A + (size_t)r*KDIM + HDIM + 2*t);
    float f0=bflo(v), f1=bfhi(v);
    s0+=f0; q0+=f0*f0; s1+=f1; q1+=f1*f1;
  }
  atomicAdd(&stats[2*t],     s0); atomicAdd(&stats[2*t+1],     s1);
  atomicAdd(&stats[512+2*t], q0); atomicAdd(&stats[512+2*t+1], q1);
}

__global__ void k_bnfin(const float* __restrict__ stats, const float* __restrict__ gamma,
                        const float* __restrict__ beta, int layer, float* __restrict__ ss){
  int f = threadIdx.x + blockIdx.x*256;
  if (f < 512){
    float mu  = stats[f] * (1.f/N_NODES);
    float var = stats[512+f] * (1.f/N_NODES) - mu*mu;
    float rs  = rsqrtf(var + 1e-5f);
    float g = gamma[layer*512+f];
    float b = beta[layer*512+f];
    ss[f]     = g*rs;
    ss[512+f] = b - mu*g*rs;
  }
}

__global__ __launch_bounds__(256) void k_bnapply(u16* __restrict__ A, const float* __restrict__ ss){
  int c = blockIdx.x*256 + threadIdx.x;
  if (c >= N_NODES*256) return;
  int n = c >> 8, pp = c & 255;
  u16* addr = A + (size_t)n*KDIM + HDIM + 2*pp;
  u32 v = *(const u32*)addr;
  float f0 = bflo(v)*ss[2*pp]   + ss[512+2*pp];
  float f1 = bfhi(v)*ss[2*pp+1] + ss[512+2*pp+1];
  *(u32*)addr = ((u32)f2bf(f1) << 16) | (u32)f2bf(f0);
}

// ---------------- final conv (C=10) + log_softmax; one wave per node; fp32 out ----------------
__global__ __launch_bounds__(256) void k_final(const u16* __restrict__ A, const u16* __restrict__ Wf,
                                               float* __restrict__ out){
  int wv = threadIdx.x >> 6, l = threadIdx.x & 63;
  int n = blockIdx.x*4 + wv;
  if (n >= N_NODES) return;
  float acc[10];
  #pragma unroll
  for (int c=0;c<10;c++) acc[c]=0.f;
  for (int k = l*2; k < KDIM; k += 128){
    u32 va = *(const u32*)(A + (size_t)n*KDIM + k);
    float a0 = bflo(va), a1 = bfhi(va);
    #pragma unroll
    for (int c=0;c<10;c++){
      u32 vw = *(const u32*)(Wf + c*KDIM + k);
      acc[c] += a0*bflo(vw) + a1*bfhi(vw);
    }
  }
  #pragma unroll
  for (int c=0;c<10;c++)
    #pragma unroll
    for (int off=32; off; off>>=1)
      acc[c] += __shfl_down(acc[c], off);
  if (l == 0){
    float m = acc[0];
    #pragma unroll
    for (int c=1;c<10;c++) m = fmaxf(m, acc[c]);
    float s = 0.f;
    #pragma unroll
    for (int c=0;c<10;c++) s += expf(acc[c]-m);
    float lse = m + logf(s);
    #pragma unroll
    for (int c=0;c<10;c++) out[n*10+c] = acc[c]-lse;
  }
}

extern "C" void kernel_launch(void* const* d_in, const int* in_sizes, int n_in,
                              void* d_out, int out_size, void* d_ws, size_t ws_size,
                              hipStream_t stream){
  (void)in_sizes; (void)n_in; (void)out_size; (void)ws_size;
  const float* x     = (const float*)d_in[0];
  const int*   eidx  = (const int*)d_in[1];
  const float* wpr   = (const float*)d_in[2];
  const float* wpo   = (const float*)d_in[3];
  const float* wrel  = (const float*)d_in[4];
  const float* wroot = (const float*)d_in[5];
  const float* gamma = (const float*)d_in[6];
  const float* beta  = (const float*)d_in[7];
  const float* wfr   = (const float*)d_in[8];
  const float* wfo   = (const float*)d_in[9];
  const int* src  = eidx;
  const int* dstv = eidx + N_EDGES;

  char* p = (char*)d_ws;
  auto carve = [&](size_t b){ char* q = p; p += (b + 255) & ~(size_t)255; return q; };
  u16*  A0      = (u16*)carve((size_t)NPAD*KDIM*2);
  u16*  A1      = (u16*)carve((size_t)NPAD*KDIM*2);
  u16*  Wcat    = (u16*)carve((size_t)4*HDIM*KDIM*2);
  u16*  Wfin    = (u16*)carve((size_t)10*KDIM*2);
  int*  cnt     = (int*)carve(N_NODES*4);
  int*  row_ptr = (int*)carve((N_NODES+1)*4);
  int*  cursor  = (int*)carve(N_NODES*4);
  int*  csr     = (int*)carve(N_EDGES*4);
  float* inv_deg= (float*)carve(N_NODES*4);
  float* stats  = (float*)carve(1024*4);
  float* ss     = (float*)carve(1024*4);

  k_zero32<<<(N_NODES+255)/256, 256, 0, stream>>>((u32*)cnt, N_NODES);
  k_hist<<<(N_EDGES+255)/256, 256, 0, stream>>>(dstv, cnt);
  k_scan<<<1, 1024, 0, stream>>>(cnt, row_ptr, cursor, inv_deg);
  k_fill<<<(N_EDGES+255)/256, 256, 0, stream>>>(src, dstv, cursor, csr);
  k_wcat<<<4096, 256, 0, stream>>>(wpr, wpo, wrel, wroot, wfr, wfo, Wcat, Wfin);
  k_copy_x<<<5000, 256, 0, stream>>>(x, A0);
  k_agg<<<N_NODES, 256, 0, stream>>>(A0, row_ptr, cnt, csr, inv_deg, A0);

  u16* Ain = A0; u16* Aout = A1;
  for (int lyr=0; lyr<4; lyr++){
    k_gemm<<<dim3(NPAD/128, 4), 256, 0, stream>>>(Ain, Wcat + (size_t)lyr*HDIM*KDIM, Aout);
    k_zero32<<<4, 256, 0, stream>>>((u32*)stats, 1024);
    k_colstats<<<200, 256, 0, stream>>>(Aout, stats);
    k_bnfin<<<2, 256, 0, stream>>>(stats, gamma, beta, lyr, ss);
    k_bnapply<<<N_NODES, 256, 0, stream>>>(Aout, ss);
    k_agg<<<N_NODES, 256, 0, stream>>>(Aout, row_ptr, cnt, csr, inv_deg, Aout);
    u16* tmp = Ain; Ain = Aout; Aout = tmp;
  }
  k_final<<<2500, 256, 0, stream>>>(Ain, Wfin, (u16*)d_out ? (float*)d_out : (float*)d_out);
}

// Round 3
// 453.711 us; speedup vs baseline: 1.2724x; 1.2724x over previous
//
#include <hip/hip_runtime.h>
#include <hip/hip_bf16.h>

typedef unsigned short u16;
typedef unsigned int   u32;

#define N_NODES 10000
#define N_EDGES 160000
#define HDIM    512
#define KDIM    1024
#define NPAD    10112   // 79 * 128

typedef __attribute__((ext_vector_type(8))) __bf16 bf16x8;
typedef __attribute__((ext_vector_type(4))) float  f32x4;

__device__ __forceinline__ float bflo(u32 v){ return __builtin_bit_cast(float, v << 16); }
__device__ __forceinline__ float bfhi(u32 v){ return __builtin_bit_cast(float, v & 0xffff0000u); }
__device__ __forceinline__ u16   f2bf(float f){ __hip_bfloat16 h = __float2bfloat16(f); return __builtin_bit_cast(u16, h); }

// ---------------- CSR build ----------------
__global__ void k_zero32(u32* __restrict__ p, int n){
  int i = blockIdx.x*256 + threadIdx.x;
  if (i < n) p[i] = 0u;
}

__global__ void k_hist(const int* __restrict__ dst, int* __restrict__ cnt){
  int e = blockIdx.x*256 + threadIdx.x;
  if (e < N_EDGES) atomicAdd(&cnt[dst[e]], 1);
}

__global__ __launch_bounds__(1024) void k_scan(const int* __restrict__ cnt, int* __restrict__ row_ptr,
                                               int* __restrict__ cursor, float* __restrict__ inv_deg){
  __shared__ int part[1024];
  int t = threadIdx.x;
  int base = t*10;
  int local[10]; int s = 0;
  for (int i=0;i<10;i++){
    int idx = base+i;
    int v = (idx < N_NODES) ? cnt[idx] : 0;
    local[i] = s; s += v;
  }
  part[t] = s;
  __syncthreads();
  for (int off=1; off<1024; off<<=1){
    int v = (t>=off) ? part[t-off] : 0;
    __syncthreads();
    part[t] += v;
    __syncthreads();
  }
  int prev = (t==0) ? 0 : part[t-1];
  for (int i=0;i<10;i++){
    int idx = base+i;
    if (idx < N_NODES){
      int rp = prev + local[i];
      row_ptr[idx] = rp; cursor[idx] = rp;
      int c = cnt[idx];
      inv_deg[idx] = 1.0f / (float)(c > 0 ? c : 1);
    }
  }
  if (t==1023) row_ptr[N_NODES] = part[1023];
}

__global__ void k_fill(const int* __restrict__ src, const int* __restrict__ dst,
                       int* __restrict__ cursor, int* __restrict__ csr_src){
  int e = blockIdx.x*256 + threadIdx.x;
  if (e < N_EDGES){
    int pos = atomicAdd(&cursor[dst[e]], 1);
    csr_src[pos] = src[e];
  }
}

// ---------------- weight concat (fp32 -> bf16) ----------------
__global__ __launch_bounds__(256) void k_wcat(const float* __restrict__ wpr, const float* __restrict__ wpo,
                                              const float* __restrict__ wrel, const float* __restrict__ wroot,
                                              const float* __restrict__ wfr, const float* __restrict__ wfo,
                                              u16* __restrict__ Wcat, u16* __restrict__ Wfin){
  int i = blockIdx.x*256 + threadIdx.x;
  if (i < 4*512*512){
    int lyr = i >> 18;
    int r   = i & 262143;
    int o = r >> 9, k = r & 511;
    const float* R = (lyr==0) ? wpr : wrel  + (size_t)(lyr-1)*262144;
    const float* O = (lyr==0) ? wpo : wroot + (size_t)(lyr-1)*262144;
    Wcat[(size_t)lyr*524288 + (size_t)o*KDIM + k]        = f2bf(R[r]);
    Wcat[(size_t)lyr*524288 + (size_t)o*KDIM + HDIM + k] = f2bf(O[r]);
  }
  if (i < 10*512){
    int o = i >> 9, k = i & 511;
    Wfin[o*KDIM + k]        = f2bf(wfr[i]);
    Wfin[o*KDIM + HDIM + k] = f2bf(wfo[i]);
  }
}

// copy x (N x 512 fp32) into A right half (bf16, stride 1024)
__global__ __launch_bounds__(256) void k_copy_x(const float* __restrict__ x, u16* __restrict__ A){
  int c = blockIdx.x*256 + threadIdx.x;
  if (c >= N_NODES*128) return;
  int n = c >> 7, o = (c & 127)*4;
  float4 v = *(const float4*)(x + (size_t)n*HDIM + o);
  ushort4 b;
  b.x = f2bf(v.x); b.y = f2bf(v.y); b.z = f2bf(v.z); b.w = f2bf(v.w);
  *(ushort4*)(A + (size_t)n*KDIM + HDIM + o) = b;
}

// mean-aggregate: A[n][0:512] = inv_deg[n] * sum_{s in nbrs(n)} A[s][512:1024]
// 4 waves per node; each wave loads a full 1KB row (uint4/lane); LDS cross-wave reduce.
__global__ __launch_bounds__(256) void k_agg(const u16* __restrict__ Abuf,
                                             const int* __restrict__ row_ptr, const int* __restrict__ cnt,
                                             const int* __restrict__ csr_src, const float* __restrict__ inv_deg,
                                             u16* __restrict__ Aleft){
  int n = blockIdx.x;
  int t = threadIdx.x, l = t & 63, w = t >> 6;
  int start = row_ptr[n], num = cnt[n];
  float acc[8];
  #pragma unroll
  for (int i=0;i<8;i++) acc[i]=0.f;

  int j = w;
  int sNext = (j < num) ? csr_src[start + j] : 0;
  while (j < num){
    int s = sNext;
    int j2 = j + 4;
    sNext = (j2 < num) ? csr_src[start + j2] : 0;
    uint4 v = *(const uint4*)(Abuf + (size_t)s*KDIM + HDIM + l*8);
    acc[0]+=bflo(v.x); acc[1]+=bfhi(v.x);
    acc[2]+=bflo(v.y); acc[3]+=bfhi(v.y);
    acc[4]+=bflo(v.z); acc[5]+=bfhi(v.z);
    acc[6]+=bflo(v.w); acc[7]+=bfhi(v.w);
    j = j2;
  }
  __shared__ float red[4][512];
  #pragma unroll
  for (int i=0;i<8;i++) red[w][l*8+i] = acc[i];
  __syncthreads();
  float id = inv_deg[n];
  int c = t*2;
  float a0 = (red[0][c]  +red[1][c]  +red[2][c]  +red[3][c]  ) * id;
  float a1 = (red[0][c+1]+red[1][c+1]+red[2][c+1]+red[3][c+1]) * id;
  u32 o = ((u32)f2bf(a1) << 16) | (u32)f2bf(a0);
  *(u32*)(Aleft + (size_t)n*KDIM + c) = o;
}

// ---------------- split-K GEMM: P[z][row][col] = sum_{k in z-half} A[row][k]*W[col][k] ----------------
__global__ __launch_bounds__(256) void k_gemm(const u16* __restrict__ A, const u16* __restrict__ W,
                                              float* __restrict__ P){
  __shared__ __align__(16) u16 As[128*32];
  __shared__ __align__(16) u16 Bs[128*32];
  const int t  = threadIdx.x;
  const int l  = t & 63;
  const int wv = t >> 6;
  const int wm = wv >> 1, wn = wv & 1;
  const int m0 = blockIdx.x * 128;
  const int n0 = blockIdx.y * 128;
  const int zb = blockIdx.z * 512;

  const int c0 = t, c1 = t + 256;
  const size_t gA0 = (size_t)(m0 + (c0>>2))*KDIM + ((c0&3)*8) + zb;
  const size_t gA1 = (size_t)(m0 + (c1>>2))*KDIM + ((c1&3)*8) + zb;
  const size_t gB0 = (size_t)(n0 + (c0>>2))*KDIM + ((c0&3)*8) + zb;
  const size_t gB1 = (size_t)(n0 + (c1>>2))*KDIM + ((c1&3)*8) + zb;

  f32x4 acc[4][4];
  #pragma unroll
  for (int i=0;i<4;i++)
    #pragma unroll
    for (int j=0;j<4;j++)
      acc[i][j] = f32x4{0.f,0.f,0.f,0.f};

  const int aoff = (wm*64 + (l&15))*32 + (l>>4)*8;
  const int boff = (wn*64 + (l&15))*32 + (l>>4)*8;

  for (int k0 = 0; k0 < 512; k0 += 32){
    __builtin_amdgcn_global_load_lds((const __attribute__((address_space(1))) void*)(A + gA0 + k0),
                                     (__attribute__((address_space(3))) void*)(As + c0*8), 16, 0, 0);
    __builtin_amdgcn_global_load_lds((const __attribute__((address_space(1))) void*)(A + gA1 + k0),
                                     (__attribute__((address_space(3))) void*)(As + c1*8), 16, 0, 0);
    __builtin_amdgcn_global_load_lds((const __attribute__((address_space(1))) void*)(W + gB0 + k0),
                                     (__attribute__((address_space(3))) void*)(Bs + c0*8), 16, 0, 0);
    __builtin_amdgcn_global_load_lds((const __attribute__((address_space(1))) void*)(W + gB1 + k0),
                                     (__attribute__((address_space(3))) void*)(Bs + c1*8), 16, 0, 0);
    __syncthreads();
    bf16x8 af[4], bfr[4];
    #pragma unroll
    for (int mt=0; mt<4; mt++)
      af[mt] = *(const bf16x8*)(As + aoff + mt*16*32);
    #pragma unroll
    for (int nt=0; nt<4; nt++)
      bfr[nt] = *(const bf16x8*)(Bs + boff + nt*16*32);
    #pragma unroll
    for (int mt=0; mt<4; mt++)
      #pragma unroll
      for (int nt=0; nt<4; nt++)
        acc[mt][nt] = __builtin_amdgcn_mfma_f32_16x16x32_bf16(af[mt], bfr[nt], acc[mt][nt], 0, 0, 0);
    __syncthreads();
  }

  float* Pz = P + (size_t)blockIdx.z*NPAD*512;
  #pragma unroll
  for (int mt=0; mt<4; mt++){
    #pragma unroll
    for (int nt=0; nt<4; nt++){
      const int col = n0 + wn*64 + nt*16 + (l & 15);
      #pragma unroll
      for (int r=0; r<4; r++){
        const int row = m0 + wm*64 + mt*16 + (l>>4)*4 + r;
        Pz[(size_t)row*512 + col] = acc[mt][nt][r];
      }
    }
  }
}

// ---------------- combine: h = relu(P0+P1+bias) -> bf16 A right half; fused BN col stats ----------------
__global__ __launch_bounds__(256) void k_combine(const float* __restrict__ P, const float* __restrict__ bias,
                                                 u16* __restrict__ A, float* __restrict__ stats){
  __shared__ float reds[4][64][8];
  __shared__ float redq[4][64][8];
  int b = blockIdx.x;            // 64 rows per block
  int t = threadIdx.x;
  int cg = t & 63;               // cols cg*8 .. cg*8+7
  int rs = t >> 6;               // 0..3
  int r0 = b*64;
  float bi[8];
  *(float4*)&bi[0] = *(const float4*)(bias + cg*8);
  *(float4*)&bi[4] = *(const float4*)(bias + cg*8 + 4);
  float s[8], q[8];
  #pragma unroll
  for (int i=0;i<8;i++){ s[i]=0.f; q[i]=0.f; }
  for (int rr = rs; rr < 64; rr += 4){
    int r = r0 + rr;
    if (r >= N_NODES) break;
    const float* p0 = P + (size_t)r*512 + cg*8;
    const float* p1 = p0 + (size_t)NPAD*512;
    float v[8], ww[8];
    *(float4*)&v[0]  = *(const float4*)p0;
    *(float4*)&v[4]  = *(const float4*)(p0+4);
    *(float4*)&ww[0] = *(const float4*)p1;
    *(float4*)&ww[4] = *(const float4*)(p1+4);
    u16 ob[8];
    #pragma unroll
    for (int i=0;i<8;i++){
      float x = v[i] + ww[i] + bi[i];
      x = x > 0.f ? x : 0.f;
      s[i] += x; q[i] += x*x;
      ob[i] = f2bf(x);
    }
    *(uint4*)(A + (size_t)r*KDIM + HDIM + cg*8) = *(uint4*)ob;
  }
  #pragma unroll
  for (int i=0;i<8;i++){ reds[rs][cg][i] = s[i]; redq[rs][cg][i] = q[i]; }
  __syncthreads();
  #pragma unroll
  for (int base=0; base<512; base+=256){
    int id = base + t;           // column id 0..511
    int g = id >> 3, i = id & 7;
    float ts = reds[0][g][i]+reds[1][g][i]+reds[2][g][i]+reds[3][g][i];
    float tq = redq[0][g][i]+redq[1][g][i]+redq[2][g][i]+redq[3][g][i];
    atomicAdd(&stats[id], ts);
    atomicAdd(&stats[512+id], tq);
  }
}

// ---------------- BN finalize: a,b per feature ----------------
__global__ void k_bnfin(const float* __restrict__ stats, const float* __restrict__ gamma,
                        const float* __restrict__ beta, int layer, float* __restrict__ ss){
  int f = threadIdx.x;
  if (f < 512){
    float mu  = stats[f] * (1.f/N_NODES);
    float var = stats[512+f] * (1.f/N_NODES) - mu*mu;
    float rs  = rsqrtf(var + 1e-5f);
    float g = gamma[layer*512+f];
    float b = beta[layer*512+f];
    ss[f]     = g*rs;                 // a_f
    ss[512+f] = b - mu*g*rs;          // b_f
  }
}

// ---------------- fold BN into next weights: Wdst[o][k] = Wsrc[o][k]*a[k&511]; bias[o] = sum_k b[k&511]*Wsrc[o][k]
__global__ __launch_bounds__(256) void k_wscale(const u16* __restrict__ Wsrc, const float* __restrict__ ss,
                                                u16* __restrict__ Wdst, float* __restrict__ biasOut){
  int o = blockIdx.x;
  int t = threadIdx.x, l = t & 63, w = t >> 6;
  const u16* row = Wsrc + (size_t)o*KDIM;
  u16* drow = Wdst + (size_t)o*KDIM;
  int k = t*4;
  uint2 v = *(const uint2*)(row + k);
  float f0 = bflo(v.x), f1 = bfhi(v.x), f2 = bflo(v.y), f3 = bfhi(v.y);
  int fk = k & 511;
  float a0 = ss[fk], a1 = ss[fk+1], a2 = ss[fk+2], a3 = ss[fk+3];
  float b0 = ss[512+fk], b1 = ss[512+fk+1], b2 = ss[512+fk+2], b3 = ss[512+fk+3];
  u16 od[4];
  od[0]=f2bf(f0*a0); od[1]=f2bf(f1*a1); od[2]=f2bf(f2*a2); od[3]=f2bf(f3*a3);
  *(ushort4*)(drow + k) = *(ushort4*)od;
  float bsum = f0*b0 + f1*b1 + f2*b2 + f3*b3;
  #pragma unroll
  for (int off=32; off; off>>=1) bsum += __shfl_down(bsum, off);
  __shared__ float wred[4];
  if (l==0) wred[w] = bsum;
  __syncthreads();
  if (t==0) biasOut[o] = wred[0]+wred[1]+wred[2]+wred[3];
}

// ---------------- final conv (C=10) + log_softmax; one wave per node; fp32 out ----------------
__global__ __launch_bounds__(256) void k_final(const u16* __restrict__ A, const u16* __restrict__ Wf,
                                               const float* __restrict__ biasF, float* __restrict__ out){
  int wv = threadIdx.x >> 6, l = threadIdx.x & 63;
  int n = blockIdx.x*4 + wv;
  if (n >= N_NODES) return;
  float acc[10];
  #pragma unroll
  for (int c=0;c<10;c++) acc[c]=0.f;
  const u16* An = A + (size_t)n*KDIM;
  #pragma unroll
  for (int half=0; half<KDIM; half+=512){
    uint4 va = *(const uint4*)(An + half + l*8);
    float a0=bflo(va.x),a1=bfhi(va.x),a2=bflo(va.y),a3=bfhi(va.y);
    float a4=bflo(va.z),a5=bfhi(va.z),a6=bflo(va.w),a7=bfhi(va.w);
    #pragma unroll
    for (int c=0;c<10;c++){
      uint4 vw = *(const uint4*)(Wf + (size_t)c*KDIM + half + l*8);
      acc[c] += a0*bflo(vw.x)+a1*bfhi(vw.x)+a2*bflo(vw.y)+a3*bfhi(vw.y)
              + a4*bflo(vw.z)+a5*bfhi(vw.z)+a6*bflo(vw.w)+a7*bfhi(vw.w);
    }
  }
  #pragma unroll
  for (int c=0;c<10;c++)
    #pragma unroll
    for (int off=32; off; off>>=1)
      acc[c] += __shfl_down(acc[c], off);
  if (l == 0){
    #pragma unroll
    for (int c=0;c<10;c++) acc[c] += biasF[c];
    float m = acc[0];
    #pragma unroll
    for (int c=1;c<10;c++) m = fmaxf(m, acc[c]);
    float s = 0.f;
    #pragma unroll
    for (int c=0;c<10;c++) s += expf(acc[c]-m);
    float lse = m + logf(s);
    #pragma unroll
    for (int c=0;c<10;c++) out[n*10+c] = acc[c]-lse;
  }
}

extern "C" void kernel_launch(void* const* d_in, const int* in_sizes, int n_in,
                              void* d_out, int out_size, void* d_ws, size_t ws_size,
                              hipStream_t stream){
  (void)in_sizes; (void)n_in; (void)out_size; (void)ws_size;
  const float* x     = (const float*)d_in[0];
  const int*   eidx  = (const int*)d_in[1];
  const float* wpr   = (const float*)d_in[2];
  const float* wpo   = (const float*)d_in[3];
  const float* wrel  = (const float*)d_in[4];
  const float* wroot = (const float*)d_in[5];
  const float* gamma = (const float*)d_in[6];
  const float* beta  = (const float*)d_in[7];
  const float* wfr   = (const float*)d_in[8];
  const float* wfo   = (const float*)d_in[9];
  const int* src  = eidx;
  const int* dstv = eidx + N_EDGES;

  char* p = (char*)d_ws;
  auto carve = [&](size_t b){ char* q = p; p += (b + 255) & ~(size_t)255; return q; };
  u16*  A0      = (u16*)carve((size_t)NPAD*KDIM*2);
  u16*  A1      = (u16*)carve((size_t)NPAD*KDIM*2);
  u16*  Wcat    = (u16*)carve((size_t)4*HDIM*KDIM*2);
  u16*  Wfin    = (u16*)carve((size_t)10*KDIM*2);
  u16*  Wsc     = (u16*)carve((size_t)HDIM*KDIM*2);
  u16*  WfinSc  = (u16*)carve((size_t)10*KDIM*2);
  float* P      = (float*)carve((size_t)2*NPAD*512*4);
  // contiguous zero region: cnt (10048) + stats (4x1024) + bias0 (512)
  int*   zreg   = (int*)carve((size_t)(10048 + 4096 + 512)*4);
  int*   cnt    = zreg;
  float* stats  = (float*)(zreg + 10048);
  float* bias0  = (float*)(zreg + 10048 + 4096);
  int*  row_ptr = (int*)carve((N_NODES+1)*4);
  int*  cursor  = (int*)carve(N_NODES*4);
  int*  csr     = (int*)carve(N_EDGES*4);
  float* inv_deg= (float*)carve(N_NODES*4);
  float* ss     = (float*)carve(1024*4);
  float* biasN  = (float*)carve(512*4);
  float* biasF  = (float*)carve(512*4);

  const int NZ = 10048 + 4096 + 512;
  k_zero32<<<(NZ+255)/256, 256, 0, stream>>>((u32*)zreg, NZ);
  k_hist<<<(N_EDGES+255)/256, 256, 0, stream>>>(dstv, cnt);
  k_scan<<<1, 1024, 0, stream>>>(cnt, row_ptr, cursor, inv_deg);
  k_fill<<<(N_EDGES+255)/256, 256, 0, stream>>>(src, dstv, cursor, csr);
  k_wcat<<<4096, 256, 0, stream>>>(wpr, wpo, wrel, wroot, wfr, wfo, Wcat, Wfin);
  k_copy_x<<<5000, 256, 0, stream>>>(x, A0);
  k_agg<<<N_NODES, 256, 0, stream>>>(A0, row_ptr, cnt, csr, inv_deg, A0);

  u16* Ain = A0; u16* Aout = A1;
  for (int lyr=0; lyr<4; lyr++){
    const u16* Wthis = (lyr==0) ? Wcat : Wsc;
    const float* bthis = (lyr==0) ? bias0 : biasN;
    k_gemm<<<dim3(NPAD/128, 4, 2), 256, 0, stream>>>(Ain, Wthis, P);
    k_combine<<<(N_NODES+63)/64, 256, 0, stream>>>(P, bthis, Aout, stats + lyr*1024);
    k_bnfin<<<1, 512, 0, stream>>>(stats + lyr*1024, gamma, beta, lyr, ss);
    if (lyr < 3)
      k_wscale<<<512, 256, 0, stream>>>(Wcat + (size_t)(lyr+1)*HDIM*KDIM, ss, Wsc, biasN);
    else
      k_wscale<<<10, 256, 0, stream>>>(Wfin, ss, WfinSc, biasF);
    k_agg<<<N_NODES, 256, 0, stream>>>(Aout, row_ptr, cnt, csr, inv_deg, Aout);
    u16* tmp = Ain; Ain = Aout; Aout = tmp;
  }
  k_final<<<2500, 256, 0, stream>>>(Ain, WfinSc, biasF, (float*)d_out);
}

// Round 4
// 385.080 us; speedup vs baseline: 1.4992x; 1.1782x over previous
//
#include <hip/hip_runtime.h>
#include <hip/hip_bf16.h>

typedef unsigned short u16;
typedef unsigned int   u32;

#define N_NODES 10000
#define N_EDGES 160000
#define HDIM    512
#define KDIM    1024
#define NPAD    10112   // 79 * 128

typedef __attribute__((ext_vector_type(8))) __bf16 bf16x8;
typedef __attribute__((ext_vector_type(4))) float  f32x4;

__device__ __forceinline__ float bflo(u32 v){ return __builtin_bit_cast(float, v << 16); }
__device__ __forceinline__ float bfhi(u32 v){ return __builtin_bit_cast(float, v & 0xffff0000u); }
__device__ __forceinline__ u16   f2bf(float f){ __hip_bfloat16 h = __float2bfloat16(f); return __builtin_bit_cast(u16, h); }

// ---------------- CSR build ----------------
__global__ void k_hist(const int* __restrict__ dst, int* __restrict__ cnt){
  int e = blockIdx.x*256 + threadIdx.x;
  if (e < N_EDGES) atomicAdd(&cnt[dst[e]], 1);
}

__global__ __launch_bounds__(1024) void k_scan(const int* __restrict__ cnt, int* __restrict__ row_ptr,
                                               int* __restrict__ cursor, float* __restrict__ inv_deg){
  __shared__ int part[1024];
  int t = threadIdx.x;
  int base = t*10;
  int local[10]; int s = 0;
  for (int i=0;i<10;i++){
    int idx = base+i;
    int v = (idx < N_NODES) ? cnt[idx] : 0;
    local[i] = s; s += v;
  }
  part[t] = s;
  __syncthreads();
  for (int off=1; off<1024; off<<=1){
    int v = (t>=off) ? part[t-off] : 0;
    __syncthreads();
    part[t] += v;
    __syncthreads();
  }
  int prev = (t==0) ? 0 : part[t-1];
  for (int i=0;i<10;i++){
    int idx = base+i;
    if (idx < N_NODES){
      int rp = prev + local[i];
      row_ptr[idx] = rp; cursor[idx] = rp;
      int c = cnt[idx];
      inv_deg[idx] = 1.0f / (float)(c > 0 ? c : 1);
    }
  }
  if (t==1023) row_ptr[N_NODES] = part[1023];
}

__global__ void k_fill(const int* __restrict__ src, const int* __restrict__ dst,
                       int* __restrict__ cursor, int* __restrict__ csr_src){
  int e = blockIdx.x*256 + threadIdx.x;
  if (e < N_EDGES){
    int pos = atomicAdd(&cursor[dst[e]], 1);
    csr_src[pos] = src[e];
  }
}

// ---------------- prep: wcat (fp32->bf16 concat) + copy_x + zero scratch, one launch ----------------
#define NZERO 14656   // cnt(10048) + stats(4096) + bias0(512)
__global__ __launch_bounds__(256) void k_prep(const float* __restrict__ wpr, const float* __restrict__ wpo,
                                              const float* __restrict__ wrel, const float* __restrict__ wroot,
                                              const float* __restrict__ wfr, const float* __restrict__ wfo,
                                              const float* __restrict__ x,
                                              u16* __restrict__ Wcat, u16* __restrict__ Wfin,
                                              u16* __restrict__ A, u32* __restrict__ zreg){
  int b = blockIdx.x, t = threadIdx.x;
  if (b < 4096){
    int i = b*256 + t;
    int lyr = i >> 18;
    int r   = i & 262143;
    int o = r >> 9, k = r & 511;
    const float* R = (lyr==0) ? wpr : wrel  + (size_t)(lyr-1)*262144;
    const float* O = (lyr==0) ? wpo : wroot + (size_t)(lyr-1)*262144;
    Wcat[(size_t)lyr*524288 + (size_t)o*KDIM + k]        = f2bf(R[r]);
    Wcat[(size_t)lyr*524288 + (size_t)o*KDIM + HDIM + k] = f2bf(O[r]);
    if (i < 10*512){
      int oo = i >> 9, kk = i & 511;
      Wfin[oo*KDIM + kk]        = f2bf(wfr[i]);
      Wfin[oo*KDIM + HDIM + kk] = f2bf(wfo[i]);
    }
  } else if (b < 9096){
    int c = (b-4096)*256 + t;
    int n = c >> 7, o = (c & 127)*4;
    float4 v = *(const float4*)(x + (size_t)n*HDIM + o);
    ushort4 bb;
    bb.x = f2bf(v.x); bb.y = f2bf(v.y); bb.z = f2bf(v.z); bb.w = f2bf(v.w);
    *(ushort4*)(A + (size_t)n*KDIM + HDIM + o) = bb;
  } else {
    int i = (b-9096)*256 + t;
    if (i < NZERO) zreg[i] = 0u;
  }
}

// mean-aggregate: A[n][0:512] = inv_deg[n] * sum_{s in nbrs(n)} A[s][512:1024]
__global__ __launch_bounds__(256) void k_agg(const u16* __restrict__ Abuf,
                                             const int* __restrict__ row_ptr, const int* __restrict__ cnt,
                                             const int* __restrict__ csr_src, const float* __restrict__ inv_deg,
                                             u16* __restrict__ Aleft){
  int n = blockIdx.x;
  int t = threadIdx.x, l = t & 63, w = t >> 6;
  int start = row_ptr[n], num = cnt[n];
  float acc[8];
  #pragma unroll
  for (int i=0;i<8;i++) acc[i]=0.f;

  int j = w;
  int sNext = (j < num) ? csr_src[start + j] : 0;
  while (j < num){
    int s = sNext;
    int j2 = j + 4;
    sNext = (j2 < num) ? csr_src[start + j2] : 0;
    uint4 v = *(const uint4*)(Abuf + (size_t)s*KDIM + HDIM + l*8);
    acc[0]+=bflo(v.x); acc[1]+=bfhi(v.x);
    acc[2]+=bflo(v.y); acc[3]+=bfhi(v.y);
    acc[4]+=bflo(v.z); acc[5]+=bfhi(v.z);
    acc[6]+=bflo(v.w); acc[7]+=bfhi(v.w);
    j = j2;
  }
  __shared__ float red[4][512];
  #pragma unroll
  for (int i=0;i<8;i++) red[w][l*8+i] = acc[i];
  __syncthreads();
  float id = inv_deg[n];
  int c = t*2;
  float a0 = (red[0][c]  +red[1][c]  +red[2][c]  +red[3][c]  ) * id;
  float a1 = (red[0][c+1]+red[1][c+1]+red[2][c+1]+red[3][c+1]) * id;
  u32 o = ((u32)f2bf(a1) << 16) | (u32)f2bf(a0);
  *(u32*)(Aleft + (size_t)n*KDIM + c) = o;
}

// ---------------- GEMM 64x128 tile, K=1024, fused bias+relu+bf16 store+BN stats ----------------
__global__ __launch_bounds__(256) void k_gemm(const u16* __restrict__ A, const u16* __restrict__ W,
                                              const float* __restrict__ bias,
                                              u16* __restrict__ Hout, float* __restrict__ stats){
  __shared__ __align__(16) u16 As[64*32];
  __shared__ __align__(16) u16 Bs[128*32];
  __shared__ float red_s[2][128];
  __shared__ float red_q[2][128];
  const int t  = threadIdx.x;
  const int l  = t & 63;
  const int wv = t >> 6;
  const int wm = wv >> 1, wn = wv & 1;
  const int m0 = blockIdx.x * 64;
  const int n0 = blockIdx.y * 128;

  const int c1 = t + 256;
  const size_t gA  = (size_t)(m0 + (t>>2))*KDIM + ((t&3)*8);
  const size_t gB0 = (size_t)(n0 + (t>>2))*KDIM + ((t&3)*8);
  const size_t gB1 = (size_t)(n0 + (c1>>2))*KDIM + ((c1&3)*8);

  f32x4 acc[2][4];
  #pragma unroll
  for (int i=0;i<2;i++)
    #pragma unroll
    for (int j=0;j<4;j++)
      acc[i][j] = f32x4{0.f,0.f,0.f,0.f};

  const int aoff = (wm*32 + (l&15))*32 + (l>>4)*8;
  const int boff = (wn*64 + (l&15))*32 + (l>>4)*8;

  for (int k0 = 0; k0 < KDIM; k0 += 32){
    __builtin_amdgcn_global_load_lds((const __attribute__((address_space(1))) void*)(A + gA + k0),
                                     (__attribute__((address_space(3))) void*)(As + t*8), 16, 0, 0);
    __builtin_amdgcn_global_load_lds((const __attribute__((address_space(1))) void*)(W + gB0 + k0),
                                     (__attribute__((address_space(3))) void*)(Bs + t*8), 16, 0, 0);
    __builtin_amdgcn_global_load_lds((const __attribute__((address_space(1))) void*)(W + gB1 + k0),
                                     (__attribute__((address_space(3))) void*)(Bs + c1*8), 16, 0, 0);
    __syncthreads();
    bf16x8 af[2], bfr[4];
    af[0] = *(const bf16x8*)(As + aoff);
    af[1] = *(const bf16x8*)(As + aoff + 16*32);
    #pragma unroll
    for (int nt=0; nt<4; nt++)
      bfr[nt] = *(const bf16x8*)(Bs + boff + nt*16*32);
    #pragma unroll
    for (int mt=0; mt<2; mt++)
      #pragma unroll
      for (int nt=0; nt<4; nt++)
        acc[mt][nt] = __builtin_amdgcn_mfma_f32_16x16x32_bf16(af[mt], bfr[nt], acc[mt][nt], 0, 0, 0);
    __syncthreads();
  }

  // epilogue: bias + relu + bf16 store + column stats
  float bi[4], sc[4], qc[4];
  #pragma unroll
  for (int nt=0; nt<4; nt++){
    bi[nt] = bias[n0 + wn*64 + nt*16 + (l & 15)];
    sc[nt] = 0.f; qc[nt] = 0.f;
  }
  #pragma unroll
  for (int nt=0; nt<4; nt++){
    const int col = n0 + wn*64 + nt*16 + (l & 15);
    #pragma unroll
    for (int mt=0; mt<2; mt++){
      #pragma unroll
      for (int r=0; r<4; r++){
        const int row = m0 + wm*32 + mt*16 + (l>>4)*4 + r;
        if (row < N_NODES){
          float v = acc[mt][nt][r] + bi[nt];
          v = v > 0.f ? v : 0.f;
          sc[nt] += v; qc[nt] += v*v;
          Hout[(size_t)row*KDIM + HDIM + col] = f2bf(v);
        }
      }
    }
  }
  #pragma unroll
  for (int nt=0; nt<4; nt++){
    float s = sc[nt], q = qc[nt];
    s += __shfl_xor(s, 16); s += __shfl_xor(s, 32);
    q += __shfl_xor(q, 16); q += __shfl_xor(q, 32);
    if (l < 16){
      red_s[wm][wn*64 + nt*16 + l] = s;
      red_q[wm][wn*64 + nt*16 + l] = q;
    }
  }
  __syncthreads();
  if (t < 128){
    atomicAdd(&stats[n0 + t],       red_s[0][t] + red_s[1][t]);
    atomicAdd(&stats[512 + n0 + t], red_q[0][t] + red_q[1][t]);
  }
}

// ---------------- wscale with fused BN finalize: Wdst[o][k]=Wsrc[o][k]*a[k&511]; bias[o]=sum b*Wsrc ----------------
__global__ __launch_bounds__(256) void k_wscale(const u16* __restrict__ Wsrc, const float* __restrict__ stats,
                                                const float* __restrict__ gamma, const float* __restrict__ beta,
                                                int layer, u16* __restrict__ Wdst, float* __restrict__ biasOut){
  int o = blockIdx.x;
  int t = threadIdx.x, l = t & 63, w = t >> 6;
  int k = t*4;
  int fk = k & 511;
  float a[4], b[4];
  #pragma unroll
  for (int i=0;i<4;i++){
    int f = fk + i;
    float mu  = stats[f] * (1.f/N_NODES);
    float var = stats[512+f] * (1.f/N_NODES) - mu*mu;
    float rs  = rsqrtf(var + 1e-5f);
    float g = gamma[layer*512+f];
    a[i] = g*rs;
    b[i] = beta[layer*512+f] - mu*a[i];
  }
  const u16* row = Wsrc + (size_t)o*KDIM;
  uint2 v = *(const uint2*)(row + k);
  float f0 = bflo(v.x), f1 = bfhi(v.x), f2 = bflo(v.y), f3 = bfhi(v.y);
  u16 od[4];
  od[0]=f2bf(f0*a[0]); od[1]=f2bf(f1*a[1]); od[2]=f2bf(f2*a[2]); od[3]=f2bf(f3*a[3]);
  *(ushort4*)(Wdst + (size_t)o*KDIM + k) = *(ushort4*)od;
  float bsum = f0*b[0] + f1*b[1] + f2*b[2] + f3*b[3];
  #pragma unroll
  for (int off=32; off; off>>=1) bsum += __shfl_down(bsum, off);
  __shared__ float wred[4];
  if (l==0) wred[w] = bsum;
  __syncthreads();
  if (t==0) biasOut[o] = wred[0]+wred[1]+wred[2]+wred[3];
}

// ---------------- final conv (C=10) + log_softmax; one wave per node; fp32 out ----------------
__global__ __launch_bounds__(256) void k_final(const u16* __restrict__ A, const u16* __restrict__ Wf,
                                               const float* __restrict__ biasF, float* __restrict__ out){
  int wv = threadIdx.x >> 6, l = threadIdx.x & 63;
  int n = blockIdx.x*4 + wv;
  if (n >= N_NODES) return;
  float acc[10];
  #pragma unroll
  for (int c=0;c<10;c++) acc[c]=0.f;
  const u16* An = A + (size_t)n*KDIM;
  #pragma unroll
  for (int half=0; half<KDIM; half+=512){
    uint4 va = *(const uint4*)(An + half + l*8);
    float a0=bflo(va.x),a1=bfhi(va.x),a2=bflo(va.y),a3=bfhi(va.y);
    float a4=bflo(va.z),a5=bfhi(va.z),a6=bflo(va.w),a7=bfhi(va.w);
    #pragma unroll
    for (int c=0;c<10;c++){
      uint4 vw = *(const uint4*)(Wf + (size_t)c*KDIM + half + l*8);
      acc[c] += a0*bflo(vw.x)+a1*bfhi(vw.x)+a2*bflo(vw.y)+a3*bfhi(vw.y)
              + a4*bflo(vw.z)+a5*bfhi(vw.z)+a6*bflo(vw.w)+a7*bfhi(vw.w);
    }
  }
  #pragma unroll
  for (int c=0;c<10;c++)
    #pragma unroll
    for (int off=32; off; off>>=1)
      acc[c] += __shfl_down(acc[c], off);
  if (l == 0){
    #pragma unroll
    for (int c=0;c<10;c++) acc[c] += biasF[c];
    float m = acc[0];
    #pragma unroll
    for (int c=1;c<10;c++) m = fmaxf(m, acc[c]);
    float s = 0.f;
    #pragma unroll
    for (int c=0;c<10;c++) s += expf(acc[c]-m);
    float lse = m + logf(s);
    #pragma unroll
    for (int c=0;c<10;c++) out[n*10+c] = acc[c]-lse;
  }
}

extern "C" void kernel_launch(void* const* d_in, const int* in_sizes, int n_in,
                              void* d_out, int out_size, void* d_ws, size_t ws_size,
                              hipStream_t stream){
  (void)in_sizes; (void)n_in; (void)out_size; (void)ws_size;
  const float* x     = (const float*)d_in[0];
  const int*   eidx  = (const int*)d_in[1];
  const float* wpr   = (const float*)d_in[2];
  const float* wpo   = (const float*)d_in[3];
  const float* wrel  = (const float*)d_in[4];
  const float* wroot = (const float*)d_in[5];
  const float* gamma = (const float*)d_in[6];
  const float* beta  = (const float*)d_in[7];
  const float* wfr   = (const float*)d_in[8];
  const float* wfo   = (const float*)d_in[9];
  const int* src  = eidx;
  const int* dstv = eidx + N_EDGES;

  char* p = (char*)d_ws;
  auto carve = [&](size_t b){ char* q = p; p += (b + 255) & ~(size_t)255; return q; };
  u16*  A0      = (u16*)carve((size_t)NPAD*KDIM*2);
  u16*  A1      = (u16*)carve((size_t)NPAD*KDIM*2);
  u16*  Wcat    = (u16*)carve((size_t)4*HDIM*KDIM*2);
  u16*  Wfin    = (u16*)carve((size_t)10*KDIM*2);
  u16*  Wsc     = (u16*)carve((size_t)HDIM*KDIM*2);
  u16*  WfinSc  = (u16*)carve((size_t)10*KDIM*2);
  // contiguous zero region: cnt (10048) + stats (4x1024) + bias0 (512)
  int*   zreg   = (int*)carve((size_t)NZERO*4);
  int*   cnt    = zreg;
  float* stats  = (float*)(zreg + 10048);
  float* bias0  = (float*)(zreg + 10048 + 4096);
  int*  row_ptr = (int*)carve((N_NODES+1)*4);
  int*  cursor  = (int*)carve(N_NODES*4);
  int*  csr     = (int*)carve(N_EDGES*4);
  float* inv_deg= (float*)carve(N_NODES*4);
  float* biasN  = (float*)carve(512*4);
  float* biasF  = (float*)carve(512*4);

  k_prep<<<9154, 256, 0, stream>>>(wpr, wpo, wrel, wroot, wfr, wfo, x, Wcat, Wfin, A0, (u32*)zreg);
  k_hist<<<(N_EDGES+255)/256, 256, 0, stream>>>(dstv, cnt);
  k_scan<<<1, 1024, 0, stream>>>(cnt, row_ptr, cursor, inv_deg);
  k_fill<<<(N_EDGES+255)/256, 256, 0, stream>>>(src, dstv, cursor, csr);
  k_agg<<<N_NODES, 256, 0, stream>>>(A0, row_ptr, cnt, csr, inv_deg, A0);

  u16* Ain = A0; u16* Aout = A1;
  for (int lyr=0; lyr<4; lyr++){
    const u16* Wthis = (lyr==0) ? Wcat : Wsc;
    const float* bthis = (lyr==0) ? bias0 : biasN;
    k_gemm<<<dim3(158, 4), 256, 0, stream>>>(Ain, Wthis, bthis, Aout, stats + lyr*1024);
    if (lyr < 3)
      k_wscale<<<512, 256, 0, stream>>>(Wcat + (size_t)(lyr+1)*HDIM*KDIM, stats + lyr*1024,
                                        gamma, beta, lyr, Wsc, biasN);
    else
      k_wscale<<<10, 256, 0, stream>>>(Wfin, stats + lyr*1024, gamma, beta, lyr, WfinSc, biasF);
    k_agg<<<N_NODES, 256, 0, stream>>>(Aout, row_ptr, cnt, csr, inv_deg, Aout);
    u16* tmp = Ain; Ain = Aout; Aout = tmp;
  }
  k_final<<<2500, 256, 0, stream>>>(Ain, WfinSc, biasF, (float*)d_out);
}

// Round 5
// 354.458 us; speedup vs baseline: 1.6287x; 1.0864x over previous
//
#include <hip/hip_runtime.h>
#include <hip/hip_bf16.h>

typedef unsigned short u16;
typedef unsigned int   u32;

#define N_NODES 10000
#define N_EDGES 160000
#define HDIM    512
#define KDIM    1024
#define NPAD    10112   // 79 * 128

typedef __attribute__((ext_vector_type(8))) __bf16 bf16x8;
typedef __attribute__((ext_vector_type(4))) float  f32x4;

__device__ __forceinline__ float bflo(u32 v){ return __builtin_bit_cast(float, v << 16); }
__device__ __forceinline__ float bfhi(u32 v){ return __builtin_bit_cast(float, v & 0xffff0000u); }
__device__ __forceinline__ u16   f2bf(float f){ __hip_bfloat16 h = __float2bfloat16(f); return __builtin_bit_cast(u16, h); }

// ---------------- CSR build ----------------
__global__ void k_hist(const int* __restrict__ dst, int* __restrict__ cnt){
  int e = blockIdx.x*256 + threadIdx.x;
  if (e < N_EDGES) atomicAdd(&cnt[dst[e]], 1);
}

__global__ __launch_bounds__(1024) void k_scan(const int* __restrict__ cnt, int* __restrict__ row_ptr,
                                               int* __restrict__ cursor, float* __restrict__ inv_deg){
  __shared__ int part[1024];
  int t = threadIdx.x;
  int base = t*10;
  int local[10]; int s = 0;
  for (int i=0;i<10;i++){
    int idx = base+i;
    int v = (idx < N_NODES) ? cnt[idx] : 0;
    local[i] = s; s += v;
  }
  part[t] = s;
  __syncthreads();
  for (int off=1; off<1024; off<<=1){
    int v = (t>=off) ? part[t-off] : 0;
    __syncthreads();
    part[t] += v;
    __syncthreads();
  }
  int prev = (t==0) ? 0 : part[t-1];
  for (int i=0;i<10;i++){
    int idx = base+i;
    if (idx < N_NODES){
      int rp = prev + local[i];
      row_ptr[idx] = rp; cursor[idx] = rp;
      int c = cnt[idx];
      inv_deg[idx] = 1.0f / (float)(c > 0 ? c : 1);
    }
  }
  if (t==1023) row_ptr[N_NODES] = part[1023];
}

__global__ void k_fill(const int* __restrict__ src, const int* __restrict__ dst,
                       int* __restrict__ cursor, int* __restrict__ csr_src){
  int e = blockIdx.x*256 + threadIdx.x;
  if (e < N_EDGES){
    int pos = atomicAdd(&cursor[dst[e]], 1);
    csr_src[pos] = src[e];
  }
}

// ---------------- prep: wcat (fp32->bf16 concat) + copy_x + zero scratch, one launch ----------------
#define NZERO 14656   // cnt(10048) + stats(4096) + bias0(512)
__global__ __launch_bounds__(256) void k_prep(const float* __restrict__ wpr, const float* __restrict__ wpo,
                                              const float* __restrict__ wrel, const float* __restrict__ wroot,
                                              const float* __restrict__ wfr, const float* __restrict__ wfo,
                                              const float* __restrict__ x,
                                              u16* __restrict__ Wcat, u16* __restrict__ Wfin,
                                              u16* __restrict__ A, u32* __restrict__ zreg){
  int b = blockIdx.x, t = threadIdx.x;
  if (b < 4096){
    int i = b*256 + t;
    int lyr = i >> 18;
    int r   = i & 262143;
    int o = r >> 9, k = r & 511;
    const float* R = (lyr==0) ? wpr : wrel  + (size_t)(lyr-1)*262144;
    const float* O = (lyr==0) ? wpo : wroot + (size_t)(lyr-1)*262144;
    Wcat[(size_t)lyr*524288 + (size_t)o*KDIM + k]        = f2bf(R[r]);
    Wcat[(size_t)lyr*524288 + (size_t)o*KDIM + HDIM + k] = f2bf(O[r]);
    if (i < 10*512){
      int oo = i >> 9, kk = i & 511;
      Wfin[oo*KDIM + kk]        = f2bf(wfr[i]);
      Wfin[oo*KDIM + HDIM + kk] = f2bf(wfo[i]);
    }
  } else if (b < 9096){
    int c = (b-4096)*256 + t;
    int n = c >> 7, o = (c & 127)*4;
    float4 v = *(const float4*)(x + (size_t)n*HDIM + o);
    ushort4 bb;
    bb.x = f2bf(v.x); bb.y = f2bf(v.y); bb.z = f2bf(v.z); bb.w = f2bf(v.w);
    *(ushort4*)(A + (size_t)n*KDIM + HDIM + o) = bb;
  } else {
    int i = (b-9096)*256 + t;
    if (i < NZERO) zreg[i] = 0u;
  }
}

// mean-aggregate: A[n][0:512] = inv_deg[n] * sum_{s in nbrs(n)} A[s][512:1024]
// 4 waves per node; each wave loads full 1KB rows (uint4/lane), 2 rows in flight.
__global__ __launch_bounds__(256) void k_agg(const u16* __restrict__ Abuf,
                                             const int* __restrict__ row_ptr, const int* __restrict__ cnt,
                                             const int* __restrict__ csr_src, const float* __restrict__ inv_deg,
                                             u16* __restrict__ Aleft){
  int n = blockIdx.x;
  int t = threadIdx.x, l = t & 63, w = t >> 6;
  int start = row_ptr[n], num = cnt[n];
  float acc[8];
  #pragma unroll
  for (int i=0;i<8;i++) acc[i]=0.f;

  int j = w;
  while (j + 4 < num){
    int s0 = csr_src[start + j];
    int s1 = csr_src[start + j + 4];
    uint4 v0 = *(const uint4*)(Abuf + (size_t)s0*KDIM + HDIM + l*8);
    uint4 v1 = *(const uint4*)(Abuf + (size_t)s1*KDIM + HDIM + l*8);
    acc[0]+=bflo(v0.x); acc[1]+=bfhi(v0.x);
    acc[2]+=bflo(v0.y); acc[3]+=bfhi(v0.y);
    acc[4]+=bflo(v0.z); acc[5]+=bfhi(v0.z);
    acc[6]+=bflo(v0.w); acc[7]+=bfhi(v0.w);
    acc[0]+=bflo(v1.x); acc[1]+=bfhi(v1.x);
    acc[2]+=bflo(v1.y); acc[3]+=bfhi(v1.y);
    acc[4]+=bflo(v1.z); acc[5]+=bfhi(v1.z);
    acc[6]+=bflo(v1.w); acc[7]+=bfhi(v1.w);
    j += 8;
  }
  if (j < num){
    int s = csr_src[start + j];
    uint4 v = *(const uint4*)(Abuf + (size_t)s*KDIM + HDIM + l*8);
    acc[0]+=bflo(v.x); acc[1]+=bfhi(v.x);
    acc[2]+=bflo(v.y); acc[3]+=bfhi(v.y);
    acc[4]+=bflo(v.z); acc[5]+=bfhi(v.z);
    acc[6]+=bflo(v.w); acc[7]+=bfhi(v.w);
  }
  __shared__ float red[4][512];
  #pragma unroll
  for (int i=0;i<8;i++) red[w][l*8+i] = acc[i];
  __syncthreads();
  float id = inv_deg[n];
  int c = t*2;
  float a0 = (red[0][c]  +red[1][c]  +red[2][c]  +red[3][c]  ) * id;
  float a1 = (red[0][c+1]+red[1][c+1]+red[2][c+1]+red[3][c+1]) * id;
  u32 o = ((u32)f2bf(a1) << 16) | (u32)f2bf(a0);
  *(u32*)(Aleft + (size_t)n*KDIM + c) = o;
}

// ---------------- GEMM 64x128 tile, K=1024, fused bias+relu+bf16 store+BN stats ----------------
// 1D grid, XCD-panel swizzle: y = id&3 so each XCD (id%8 round-robin) keeps ONE
// 256KB W panel L2-resident; A streams from L3.
__global__ __launch_bounds__(256) void k_gemm(const u16* __restrict__ A, const u16* __restrict__ W,
                                              const float* __restrict__ bias,
                                              u16* __restrict__ Hout, float* __restrict__ stats){
  __shared__ __align__(16) u16 As[64*32];
  __shared__ __align__(16) u16 Bs[128*32];
  __shared__ float red_s[2][128];
  __shared__ float red_q[2][128];
  const int id = blockIdx.x;
  const int t  = threadIdx.x;
  const int l  = t & 63;
  const int wv = t >> 6;
  const int wm = wv >> 1, wn = wv & 1;
  const int m0 = (id >> 2) * 64;
  const int n0 = (id & 3) * 128;

  const int c1 = t + 256;
  const size_t gA  = (size_t)(m0 + (t>>2))*KDIM + ((t&3)*8);
  const size_t gB0 = (size_t)(n0 + (t>>2))*KDIM + ((t&3)*8);
  const size_t gB1 = (size_t)(n0 + (c1>>2))*KDIM + ((c1&3)*8);

  f32x4 acc[2][4];
  #pragma unroll
  for (int i=0;i<2;i++)
    #pragma unroll
    for (int j=0;j<4;j++)
      acc[i][j] = f32x4{0.f,0.f,0.f,0.f};

  const int aoff = (wm*32 + (l&15))*32 + (l>>4)*8;
  const int boff = (wn*64 + (l&15))*32 + (l>>4)*8;

  for (int k0 = 0; k0 < KDIM; k0 += 32){
    __builtin_amdgcn_global_load_lds((const __attribute__((address_space(1))) void*)(A + gA + k0),
                                     (__attribute__((address_space(3))) void*)(As + t*8), 16, 0, 0);
    __builtin_amdgcn_global_load_lds((const __attribute__((address_space(1))) void*)(W + gB0 + k0),
                                     (__attribute__((address_space(3))) void*)(Bs + t*8), 16, 0, 0);
    __builtin_amdgcn_global_load_lds((const __attribute__((address_space(1))) void*)(W + gB1 + k0),
                                     (__attribute__((address_space(3))) void*)(Bs + c1*8), 16, 0, 0);
    __syncthreads();
    bf16x8 af[2], bfr[4];
    af[0] = *(const bf16x8*)(As + aoff);
    af[1] = *(const bf16x8*)(As + aoff + 16*32);
    #pragma unroll
    for (int nt=0; nt<4; nt++)
      bfr[nt] = *(const bf16x8*)(Bs + boff + nt*16*32);
    #pragma unroll
    for (int mt=0; mt<2; mt++)
      #pragma unroll
      for (int nt=0; nt<4; nt++)
        acc[mt][nt] = __builtin_amdgcn_mfma_f32_16x16x32_bf16(af[mt], bfr[nt], acc[mt][nt], 0, 0, 0);
    __syncthreads();
  }

  // epilogue: bias + relu + bf16 store + column stats
  float bi[4], sc[4], qc[4];
  #pragma unroll
  for (int nt=0; nt<4; nt++){
    bi[nt] = bias[n0 + wn*64 + nt*16 + (l & 15)];
    sc[nt] = 0.f; qc[nt] = 0.f;
  }
  #pragma unroll
  for (int nt=0; nt<4; nt++){
    const int col = n0 + wn*64 + nt*16 + (l & 15);
    #pragma unroll
    for (int mt=0; mt<2; mt++){
      #pragma unroll
      for (int r=0; r<4; r++){
        const int row = m0 + wm*32 + mt*16 + (l>>4)*4 + r;
        if (row < N_NODES){
          float v = acc[mt][nt][r] + bi[nt];
          v = v > 0.f ? v : 0.f;
          sc[nt] += v; qc[nt] += v*v;
          Hout[(size_t)row*KDIM + HDIM + col] = f2bf(v);
        }
      }
    }
  }
  #pragma unroll
  for (int nt=0; nt<4; nt++){
    float s = sc[nt], q = qc[nt];
    s += __shfl_xor(s, 16); s += __shfl_xor(s, 32);
    q += __shfl_xor(q, 16); q += __shfl_xor(q, 32);
    if (l < 16){
      red_s[wm][wn*64 + nt*16 + l] = s;
      red_q[wm][wn*64 + nt*16 + l] = q;
    }
  }
  __syncthreads();
  if (t < 128){
    atomicAdd(&stats[n0 + t],       red_s[0][t] + red_s[1][t]);
    atomicAdd(&stats[512 + n0 + t], red_q[0][t] + red_q[1][t]);
  }
}

// ---------------- wscale with fused BN finalize ----------------
__global__ __launch_bounds__(256) void k_wscale(const u16* __restrict__ Wsrc, const float* __restrict__ stats,
                                                const float* __restrict__ gamma, const float* __restrict__ beta,
                                                int layer, u16* __restrict__ Wdst, float* __restrict__ biasOut){
  int o = blockIdx.x;
  int t = threadIdx.x, l = t & 63, w = t >> 6;
  int k = t*4;
  int fk = k & 511;
  float a[4], b[4];
  #pragma unroll
  for (int i=0;i<4;i++){
    int f = fk + i;
    float mu  = stats[f] * (1.f/N_NODES);
    float var = stats[512+f] * (1.f/N_NODES) - mu*mu;
    float rs  = rsqrtf(var + 1e-5f);
    float g = gamma[layer*512+f];
    a[i] = g*rs;
    b[i] = beta[layer*512+f] - mu*a[i];
  }
  const u16* row = Wsrc + (size_t)o*KDIM;
  uint2 v = *(const uint2*)(row + k);
  float f0 = bflo(v.x), f1 = bfhi(v.x), f2 = bflo(v.y), f3 = bfhi(v.y);
  u16 od[4];
  od[0]=f2bf(f0*a[0]); od[1]=f2bf(f1*a[1]); od[2]=f2bf(f2*a[2]); od[3]=f2bf(f3*a[3]);
  *(ushort4*)(Wdst + (size_t)o*KDIM + k) = *(ushort4*)od;
  float bsum = f0*b[0] + f1*b[1] + f2*b[2] + f3*b[3];
  #pragma unroll
  for (int off=32; off; off>>=1) bsum += __shfl_down(bsum, off);
  __shared__ float wred[4];
  if (l==0) wred[w] = bsum;
  __syncthreads();
  if (t==0) biasOut[o] = wred[0]+wred[1]+wred[2]+wred[3];
}

// ---------------- final conv (C=10) + log_softmax; one wave per node; fp32 out ----------------
__global__ __launch_bounds__(256) void k_final(const u16* __restrict__ A, const u16* __restrict__ Wf,
                                               const float* __restrict__ biasF, float* __restrict__ out){
  int wv = threadIdx.x >> 6, l = threadIdx.x & 63;
  int n = blockIdx.x*4 + wv;
  if (n >= N_NODES) return;
  float acc[10];
  #pragma unroll
  for (int c=0;c<10;c++) acc[c]=0.f;
  const u16* An = A + (size_t)n*KDIM;
  #pragma unroll
  for (int half=0; half<KDIM; half+=512){
    uint4 va = *(const uint4*)(An + half + l*8);
    float a0=bflo(va.x),a1=bfhi(va.x),a2=bflo(va.y),a3=bfhi(va.y);
    float a4=bflo(va.z),a5=bfhi(va.z),a6=bflo(va.w),a7=bfhi(va.w);
    #pragma unroll
    for (int c=0;c<10;c++){
      uint4 vw = *(const uint4*)(Wf + (size_t)c*KDIM + half + l*8);
      acc[c] += a0*bflo(vw.x)+a1*bfhi(vw.x)+a2*bflo(vw.y)+a3*bfhi(vw.y)
              + a4*bflo(vw.z)+a5*bfhi(vw.z)+a6*bflo(vw.w)+a7*bfhi(vw.w);
    }
  }
  #pragma unroll
  for (int c=0;c<10;c++)
    #pragma unroll
    for (int off=32; off; off>>=1)
      acc[c] += __shfl_down(acc[c], off);
  if (l == 0){
    #pragma unroll
    for (int c=0;c<10;c++) acc[c] += biasF[c];
    float m = acc[0];
    #pragma unroll
    for (int c=1;c<10;c++) m = fmaxf(m, acc[c]);
    float s = 0.f;
    #pragma unroll
    for (int c=0;c<10;c++) s += expf(acc[c]-m);
    float lse = m + logf(s);
    #pragma unroll
    for (int c=0;c<10;c++) out[n*10+c] = acc[c]-lse;
  }
}

extern "C" void kernel_launch(void* const* d_in, const int* in_sizes, int n_in,
                              void* d_out, int out_size, void* d_ws, size_t ws_size,
                              hipStream_t stream){
  (void)in_sizes; (void)n_in; (void)out_size; (void)ws_size;
  const float* x     = (const float*)d_in[0];
  const int*   eidx  = (const int*)d_in[1];
  const float* wpr   = (const float*)d_in[2];
  const float* wpo   = (const float*)d_in[3];
  const float* wrel  = (const float*)d_in[4];
  const float* wroot = (const float*)d_in[5];
  const float* gamma = (const float*)d_in[6];
  const float* beta  = (const float*)d_in[7];
  const float* wfr   = (const float*)d_in[8];
  const float* wfo   = (const float*)d_in[9];
  const int* src  = eidx;
  const int* dstv = eidx + N_EDGES;

  char* p = (char*)d_ws;
  auto carve = [&](size_t b){ char* q = p; p += (b + 255) & ~(size_t)255; return q; };
  u16*  A0      = (u16*)carve((size_t)NPAD*KDIM*2);
  u16*  A1      = (u16*)carve((size_t)NPAD*KDIM*2);
  u16*  Wcat    = (u16*)carve((size_t)4*HDIM*KDIM*2);
  u16*  Wfin    = (u16*)carve((size_t)10*KDIM*2);
  u16*  Wsc     = (u16*)carve((size_t)HDIM*KDIM*2);
  u16*  WfinSc  = (u16*)carve((size_t)10*KDIM*2);
  int*   zreg   = (int*)carve((size_t)NZERO*4);
  int*   cnt    = zreg;
  float* stats  = (float*)(zreg + 10048);
  float* bias0  = (float*)(zreg + 10048 + 4096);
  int*  row_ptr = (int*)carve((N_NODES+1)*4);
  int*  cursor  = (int*)carve(N_NODES*4);
  int*  csr     = (int*)carve(N_EDGES*4);
  float* inv_deg= (float*)carve(N_NODES*4);
  float* biasN  = (float*)carve(512*4);
  float* biasF  = (float*)carve(512*4);

  k_prep<<<9154, 256, 0, stream>>>(wpr, wpo, wrel, wroot, wfr, wfo, x, Wcat, Wfin, A0, (u32*)zreg);
  k_hist<<<(N_EDGES+255)/256, 256, 0, stream>>>(dstv, cnt);
  k_scan<<<1, 1024, 0, stream>>>(cnt, row_ptr, cursor, inv_deg);
  k_fill<<<(N_EDGES+255)/256, 256, 0, stream>>>(src, dstv, cursor, csr);
  k_agg<<<N_NODES, 256, 0, stream>>>(A0, row_ptr, cnt, csr, inv_deg, A0);

  u16* Ain = A0; u16* Aout = A1;
  for (int lyr=0; lyr<4; lyr++){
    const u16* Wthis = (lyr==0) ? Wcat : Wsc;
    const float* bthis = (lyr==0) ? bias0 : biasN;
    k_gemm<<<632, 256, 0, stream>>>(Ain, Wthis, bthis, Aout, stats + lyr*1024);
    if (lyr < 3)
      k_wscale<<<512, 256, 0, stream>>>(Wcat + (size_t)(lyr+1)*HDIM*KDIM, stats + lyr*1024,
                                        gamma, beta, lyr, Wsc, biasN);
    else
      k_wscale<<<10, 256, 0, stream>>>(Wfin, stats + lyr*1024, gamma, beta, lyr, WfinSc, biasF);
    k_agg<<<N_NODES, 256, 0, stream>>>(Aout, row_ptr, cnt, csr, inv_deg, Aout);
    u16* tmp = Ain; Ain = Aout; Aout = tmp;
  }
  k_final<<<2500, 256, 0, stream>>>(Ain, WfinSc, biasF, (float*)d_out);
}